// Round 7
// baseline (372.948 us; speedup 1.0000x reference)
//
#include <hip/hip_runtime.h>
#include <hip/hip_bf16.h>

// Problem constants
#define T_TOK 4096
#define HID   2048
#define INTER 1408
#define TWO_I 2816
#define NEXP  8
#define ROWCAP 9216   // 2*T + 8*128 padding headroom

#define N8_HS  1048576   // T*HID/8
#define N8_W13 5767168   // E*TWO_I*HID/8
#define NCVT   ((N8_HS + N8_W13) / 256)   // 26624 cvt blocks

using bf16x8 = __attribute__((ext_vector_type(8))) __bf16;
using f32x4  = __attribute__((ext_vector_type(4))) float;

__device__ __forceinline__ unsigned short f2bf(float f) {
  unsigned u = __float_as_uint(f);
  u += 0x7fffu + ((u >> 16) & 1u);   // RTNE
  return (unsigned short)(u >> 16);
}

__device__ __forceinline__ void gload16(const void* g, void* l) {
  __builtin_amdgcn_global_load_lds(
      (const __attribute__((address_space(1))) void*)g,
      (__attribute__((address_space(3))) void*)l, 16, 0, 0);
}

__device__ __forceinline__ uint4 pack8(float4 a, float4 b) {
  union { unsigned short us[8]; uint4 v; } o;
  o.us[0] = f2bf(a.x); o.us[1] = f2bf(a.y); o.us[2] = f2bf(a.z); o.us[3] = f2bf(a.w);
  o.us[4] = f2bf(b.x); o.us[5] = f2bf(b.y); o.us[6] = f2bf(b.z); o.us[7] = f2bf(b.w);
  return o.v;
}

// ------- merged kernel: hs cvt + w13 cvt + routing (tail blocks) -------
__global__ void cvt2route_kernel(const float* __restrict__ hs_f, unsigned short* __restrict__ hs_b,
                                 const float* __restrict__ w13_f, unsigned short* __restrict__ w13_b,
                                 const int* __restrict__ ids, const float* __restrict__ wts,
                                 float* __restrict__ R, int* __restrict__ counts) {
  int bid = blockIdx.x;
  if (bid >= NCVT) {
    int t = (bid - NCVT) * 256 + threadIdx.x;
    if (t >= T_TOK) return;
    int e0 = ids[t * 2], e1 = ids[t * 2 + 1];
    float w0 = wts[t * 2], w1 = wts[t * 2 + 1];
#pragma unroll
    for (int ee = 0; ee < NEXP; ++ee) {
      float r = (e0 == ee ? w0 : 0.0f) + (e1 == ee ? w1 : 0.0f);
      R[t * NEXP + ee] = r;
    }
    atomicAdd(&counts[e0], 1);
    if (e1 != e0) atomicAdd(&counts[e1], 1);
    return;
  }
  int i = bid * 256 + threadIdx.x;
  const float4* p;
  uint4* o;
  int j;
  if (i < N8_HS) {
    p = reinterpret_cast<const float4*>(hs_f);
    o = reinterpret_cast<uint4*>(hs_b);
    j = i;
  } else {
    p = reinterpret_cast<const float4*>(w13_f);
    o = reinterpret_cast<uint4*>(w13_b);
    j = i - N8_HS;
  }
  o[j] = pack8(p[j * 2], p[j * 2 + 1]);
}

// ---------------- padded prefix offsets + token_list fill ----------------
__global__ void offsets_kernel(const int* __restrict__ counts,
                               int* __restrict__ offs, int* __restrict__ cursor,
                               int* __restrict__ tl) {
  if (threadIdx.x == 0) {
    int o = 0;
    for (int e = 0; e < NEXP; ++e) {
      offs[e] = o;
      cursor[e] = o;
      o += (counts[e] + 127) & ~127;
    }
    offs[NEXP] = o;
  }
  for (int i = threadIdx.x; i < ROWCAP; i += 256) tl[i] = -1;
}

// ---------------- scatter tokens into per-expert lists + inverse map ----------------
__global__ void scatter_kernel(const int* __restrict__ ids,
                               int* __restrict__ cursor, int* __restrict__ tl,
                               int* __restrict__ inv) {
  int t = blockIdx.x * 256 + threadIdx.x;
  if (t >= T_TOK) return;
  int e0 = ids[t * 2], e1 = ids[t * 2 + 1];
  int p = atomicAdd(&cursor[e0], 1);
  tl[p] = t;
  inv[t * 2] = p;
  if (e1 != e0) {
    p = atomicAdd(&cursor[e1], 1);
    tl[p] = t;
    inv[t * 2 + 1] = p;
  } else {
    inv[t * 2 + 1] = -1;   // dedup: R[t,e0] already holds w0+w1
  }
}

// ===================== 256x256 8-phase GEMM machinery =====================
// LDS map (128KB): slot S in {0, 65536}; within slot:
//   Ah0 @ +0, Ah1 @ +16384, Bh0 @ +32768, Bh1 @ +49152  (each 128 rows x 128B)
// R6 delta (front-loaded ds_reads): ALL four fragment reads (a_lo,a_hi,
// b_lo,b_hi) issue at P1/P5. Their data was published by the PREVIOUS slot
// boundary's vmcnt+barrier, not by intra-iteration barriers, so P2-P4/P6-P8
// have no read dependence on their own position -- they enter MFMA right
// after the barrier. P1's reads drain under P1's MFMA (lgkm before first use).
// Staging protocol (UNCHANGED, re-verified ledger):
//  P1: stage s1.Ah0@t1   P2: stage s1.Ah1@t1   P3: [nl] s0.Bh0@t0+2
//  P4: [nl] s0.Bh1@t0+2; vmcnt(4|0)            P5: [nl] s0.Ah0@t0+2
//  P6: [nl] s0.Ah1@t0+2  P7: [nl] s1.Bh0@t1+2  P8: [nl] s1.Bh1@t1+2; vmcnt(4)
// vmcnt(4)@P4 drains {prev P7,P8: s1.B} + {P1,P2: s1.A} = slot1 for P5-P8.
// vmcnt(4)@P8 drains {P3,P4: s0.B} + {P5,P6: s0.A} = slot0 for next iter.
// Overwrite-before-read: s0.A writes (P5/P6) >=3 barriers after P1 reads
// retire (lgkm forced before P3's a_hi use); s1.B writes (P7/P8) >=2 barriers
// after P5 reads retire. Each phase: BARR; setprio(1); 16 MFMA; setprio(0); BARR.

#define BARR do { __asm__ __volatile__("" ::: "memory"); \
                  __builtin_amdgcn_s_barrier();           \
                  __asm__ __volatile__("" ::: "memory"); } while (0)
#define VMC(n) __asm__ __volatile__("s_waitcnt vmcnt(" #n ")" ::: "memory")

#define STG(P, h, kt, slotOff, hOff)                                        \
  do {                                                                      \
    gload16(P[h][0] + (kt) * 128, smem + (slotOff) + (hOff) + chA);         \
    gload16(P[h][1] + (kt) * 128, smem + (slotOff) + (hOff) + chA + 1024);  \
  } while (0)

#define LDA(dst, S, aq)                                                     \
  do {                                                                      \
    _Pragma("unroll") for (int mi = 0; mi < 4; ++mi) {                      \
      const char* _p = smem + (S) + wmOff + ((aq) * 64 + mi * 16 + l15) * 128; \
      dst[mi][0] = *(const bf16x8*)(_p + ko0);                              \
      dst[mi][1] = *(const bf16x8*)(_p + ko1);                              \
    }                                                                       \
  } while (0)

#define LDB(dst, S, bq)                                                     \
  do {                                                                      \
    _Pragma("unroll") for (int ni = 0; ni < 2; ++ni) {                      \
      const char* _p = smem + (S) + 32768 + wnhOff +                        \
                       (wn1 * 64 + ((bq) * 2 + ni) * 16 + l15) * 128;       \
      dst[ni][0] = *(const bf16x8*)(_p + ko0);                              \
      dst[ni][1] = *(const bf16x8*)(_p + ko1);                              \
    }                                                                       \
  } while (0)

#define MFQ(A, B, aq, bq)                                                   \
  do {                                                                      \
    __builtin_amdgcn_s_setprio(1);                                          \
    _Pragma("unroll") for (int mi = 0; mi < 4; ++mi)                        \
    _Pragma("unroll") for (int ni = 0; ni < 2; ++ni) {                      \
      acc[(aq) * 4 + mi][(bq) * 2 + ni] = __builtin_amdgcn_mfma_f32_16x16x32_bf16( \
          A[mi][0], B[ni][0], acc[(aq) * 4 + mi][(bq) * 2 + ni], 0, 0, 0);  \
      acc[(aq) * 4 + mi][(bq) * 2 + ni] = __builtin_amdgcn_mfma_f32_16x16x32_bf16( \
          A[mi][1], B[ni][1], acc[(aq) * 4 + mi][(bq) * 2 + ni], 0, 0, 0);  \
    }                                                                       \
    __builtin_amdgcn_s_setprio(0);                                          \
  } while (0)

#define EIGHT_PHASES(NIT_, NL_LIM_)                                         \
  for (int i = 0; i < (NIT_); ++i) {                                        \
    const int t0 = 2 * i, t1 = t0 + 1;                                      \
    const bool nl = (i < (NL_LIM_));                                        \
    /* P1: front-load ALL slot0 fragment reads */                           \
    LDA(a_lo, 0, 0);                                                        \
    LDA(a_hi, 0, 1);                                                        \
    LDB(b_lo, 0, 0);                                                        \
    LDB(b_hi, 0, 1);                                                        \
    STG(aS, 0, t1, 65536, 0);                                               \
    BARR; MFQ(a_lo, b_lo, 0, 0); BARR;                                      \
    /* P2 */                                                                \
    STG(aS, 1, t1, 65536, 16384);                                           \
    BARR; MFQ(a_lo, b_hi, 0, 1); BARR;                                      \
    /* P3 */                                                                \
    if (nl) STG(bS, 0, t0 + 2, 0, 32768);                                   \
    BARR; MFQ(a_hi, b_hi, 1, 1); BARR;                                      \
    /* P4 */                                                                \
    if (nl) STG(bS, 1, t0 + 2, 0, 49152);                                   \
    BARR; MFQ(a_hi, b_lo, 1, 0);                                            \
    if (nl) { VMC(4); } else { VMC(0); }                                    \
    BARR;                                                                   \
    /* P5: front-load ALL slot1 fragment reads */                           \
    LDA(a_lo, 65536, 0);                                                    \
    LDA(a_hi, 65536, 1);                                                    \
    LDB(b_lo, 65536, 0);                                                    \
    LDB(b_hi, 65536, 1);                                                    \
    if (nl) STG(aS, 0, t0 + 2, 0, 0);                                       \
    BARR; MFQ(a_lo, b_lo, 0, 0); BARR;                                      \
    /* P6 */                                                                \
    if (nl) STG(aS, 1, t0 + 2, 0, 16384);                                   \
    BARR; MFQ(a_lo, b_hi, 0, 1); BARR;                                      \
    /* P7 */                                                                \
    if (nl) STG(bS, 0, t1 + 2, 65536, 32768);                               \
    BARR; MFQ(a_hi, b_hi, 1, 1); BARR;                                      \
    /* P8 */                                                                \
    if (nl) STG(bS, 1, t1 + 2, 65536, 49152);                               \
    BARR; MFQ(a_hi, b_lo, 1, 0);                                            \
    if (nl) VMC(4);                                                         \
    BARR;                                                                   \
  }

#define PROLOGUE_STAGE()                                                    \
  do {                                                                      \
    STG(aS, 0, 0, 0, 0);                                                    \
    STG(aS, 1, 0, 0, 16384);                                                \
    STG(bS, 0, 0, 0, 32768);                                                \
    STG(bS, 1, 0, 0, 49152);                                                \
    STG(bS, 0, 1, 65536, 32768);                                            \
    STG(bS, 1, 1, 65536, 49152);                                            \
    VMC(4);                                                                 \
    BARR;                                                                   \
  } while (0)

// ---------------- GEMM1 (+distributed w2 cvt): act = silu(X Wg^T)*(X Wu^T) ----
// R2-proven structure: static XCD-chunked grid, upfront w2-cvt smear (runs
// before early-exit so all 1408 blocks contribute; light blocks finish cvt
// and free their CU while heavy blocks GEMM).
__global__ __launch_bounds__(512, 2) void gemm1_kernel(
    const unsigned short* __restrict__ hs,   // T x 2048 bf16
    const unsigned short* __restrict__ w13,  // E x 2816 x 2048 bf16
    unsigned short* __restrict__ act,        // ROWCAP x 1408 bf16
    const int* __restrict__ tl, const int* __restrict__ offs,
    const float* __restrict__ w2f, unsigned short* __restrict__ w2b) {
  const int tid = threadIdx.x;
  const int lin = blockIdx.x + 11 * (blockIdx.y + 16 * blockIdx.z);  // [0,1408)

  // ---- distributed w2 conversion (before early-exit!) ----
  {
    const float4* p = reinterpret_cast<const float4*>(w2f);
    uint4* o = reinterpret_cast<uint4*>(w2b);
    int gid = lin * 512 + tid;              // 720896 threads total
#pragma unroll
    for (int q = 0; q < 4; ++q) {
      int idx = q * 720896 + gid;           // 4*720896 = 2,883,584 uint4 = whole w2
      o[idx] = pack8(p[idx * 2], p[idx * 2 + 1]);
    }
  }

  // ---- XCD-chunked tile id: nwg = 1408, q = 176 (expert -> XCD) ----
  const int work = (lin & 7) * 176 + (lin >> 3);
  const int bz = work / 176;
  const int rem = work - bz * 176;
  const int bx = rem % 11;
  const int by = rem / 11;

  const int e = bz;
  const int rbeg = offs[e], rend = offs[e + 1];
  const int m0 = rbeg + by * 256;
  if (m0 >= rend) return;
  const int n0 = bx * 128;

  __shared__ __align__(16) char smem[131072];

  const int lane = tid & 63, wave = tid >> 6;
  const int wm = wave >> 2, wn = wave & 3;
  const int l15 = lane & 15;
  const int srow = lane >> 3;
  const int scolswz = ((lane & 7) * 16) ^ (srow << 4);
  const int chA = wave * 2048;
  const int wmOff = wm * 16384;
  const int wnhOff = (wn >> 1) * 16384;
  const int wn1 = wn & 1;
  const int rsw = (lane & 7) << 4;
  const int ko0 = ((lane >> 4) * 16) ^ rsw;
  const int ko1 = (64 + (lane >> 4) * 16) ^ rsw;

  const char* hs_b = (const char*)hs;
  const char* w13_b = (const char*)w13 + (size_t)e * (TWO_I * HID * 2);

  const char* aS[2][2];
  const char* bS[2][2];
#pragma unroll
  for (int h = 0; h < 2; ++h)
#pragma unroll
    for (int it = 0; it < 2; ++it) {
      int rl = h * 128 + (wave * 2 + it) * 8 + srow;
      int grow = m0 + rl;
      int tk = (grow < rend) ? tl[grow] : 0;
      if (tk < 0) tk = 0;
      aS[h][it] = hs_b + (size_t)tk * 4096 + scolswz;
      int wg = rl >> 6, sub = rl & 63;   // B LDS row -> w13 row (gate/up packed)
      int srcB = (sub < 32) ? (n0 + wg * 32 + sub)
                            : (INTER + n0 + wg * 32 + (sub - 32));
      bS[h][it] = w13_b + (size_t)srcB * 4096 + scolswz;
    }

  f32x4 acc[8][4] = {};
  bf16x8 a_lo[4][2], a_hi[4][2], b_lo[2][2], b_hi[2][2];

  PROLOGUE_STAGE();
  EIGHT_PHASES(16, 15);   // K = 2048 -> 32 K-tiles, 16 iterations

  // epilogue: silu(g)*u -> bf16 act.  C/D: col=lane&15, row=(lane>>4)*4+j
  const bool okst = (wm == 0) || (rend - m0 >= 256);
  if (okst) {
#pragma unroll
    for (int MI = 0; MI < 8; ++MI)
#pragma unroll
      for (int j = 0; j < 4; ++j) {
        int row = m0 + wm * 128 + MI * 16 + (lane >> 4) * 4 + j;
        size_t base = (size_t)row * INTER + n0 + wn * 32;
#pragma unroll
        for (int NI = 0; NI < 2; ++NI) {
          float g = acc[MI][NI][j], u = acc[MI][NI + 2][j];
          float s = (g / (1.0f + __expf(-g))) * u;
          act[base + NI * 16 + l15] = f2bf(s);
        }
      }
  }
}

// ---------------- GEMM2: partial[p,:] = bf16( R[tl[p],e] * (act @ w2[e]^T) ) --
__global__ __launch_bounds__(512, 2) void gemm2_kernel(
    const unsigned short* __restrict__ act,  // ROWCAP x 1408 bf16
    const unsigned short* __restrict__ w2,   // E x 2048 x 1408 bf16
    const float* __restrict__ R, const int* __restrict__ tl,
    const int* __restrict__ offs, unsigned short* __restrict__ partial) {
  const int tid = threadIdx.x;
  const int lin = blockIdx.x + 8 * (blockIdx.y + 16 * blockIdx.z);  // [0,1024)
  const int work = (lin & 7) * 128 + (lin >> 3);
  const int bz = work >> 7;
  const int rem = work & 127;
  const int bx = rem & 7;
  const int by = rem >> 3;

  const int e = bz;
  const int rbeg = offs[e], rend = offs[e + 1];
  const int m0 = rbeg + by * 256;
  if (m0 >= rend) return;
  const int n0 = bx * 256;

  __shared__ __align__(16) char smem[131072];

  const int lane = tid & 63, wave = tid >> 6;
  const int wm = wave >> 2, wn = wave & 3;
  const int l15 = lane & 15;
  const int srow = lane >> 3;
  const int scolswz = ((lane & 7) * 16) ^ (srow << 4);
  const int chA = wave * 2048;
  const int wmOff = wm * 16384;
  const int wnhOff = (wn >> 1) * 16384;
  const int wn1 = wn & 1;
  const int rsw = (lane & 7) << 4;
  const int ko0 = ((lane >> 4) * 16) ^ rsw;
  const int ko1 = (64 + (lane >> 4) * 16) ^ rsw;

  const char* act_b = (const char*)act;
  const char* w2_b = (const char*)w2 + (size_t)e * (HID * INTER * 2);

  const char* aS[2][2];
  const char* bS[2][2];
#pragma unroll
  for (int h = 0; h < 2; ++h)
#pragma unroll
    for (int it = 0; it < 2; ++it) {
      int rl = h * 128 + (wave * 2 + it) * 8 + srow;
      int grow = m0 + rl;
      if (grow >= rend) grow = rbeg;           // keep reads in-bounds
      aS[h][it] = act_b + (size_t)grow * (INTER * 2) + scolswz;
      bS[h][it] = w2_b + (size_t)(n0 + rl) * (INTER * 2) + scolswz;
    }

  f32x4 acc[8][4] = {};
  bf16x8 a_lo[4][2], a_hi[4][2], b_lo[2][2], b_hi[2][2];

  PROLOGUE_STAGE();
  EIGHT_PHASES(11, 10);   // K = 1408 -> 22 K-tiles, 11 iterations

  // epilogue: weight-scale + bf16 stores (pads get sc=0)
  const bool okst = (wm == 0) || (rend - m0 >= 256);
  if (okst) {
#pragma unroll
    for (int MI = 0; MI < 8; ++MI) {
      float sc[4];
#pragma unroll
      for (int j = 0; j < 4; ++j) {
        int row = m0 + wm * 128 + MI * 16 + (lane >> 4) * 4 + j;
        int t = tl[row];
        sc[j] = t >= 0 ? R[t * NEXP + e] : 0.0f;
      }
#pragma unroll
      for (int NI = 0; NI < 4; ++NI) {
        int col = n0 + wn * 64 + NI * 16 + l15;
#pragma unroll
        for (int j = 0; j < 4; ++j) {
          int row = m0 + wm * 128 + MI * 16 + (lane >> 4) * 4 + j;
          partial[(size_t)row * HID + col] = f2bf(acc[MI][NI][j] * sc[j]);
        }
      }
    }
  }
}

// ---------------- combine: out[t,:] = partial[inv0,:] (+ partial[inv1,:]) ----
__global__ void combine_kernel(const unsigned short* __restrict__ P,
                               const int* __restrict__ inv,
                               float* __restrict__ out) {
  int idx = blockIdx.x * 256 + threadIdx.x;   // T_TOK * HID/8 threads
  int t = idx >> 8;                            // HID/8 = 256
  int c = (idx & 255) << 3;
  int p0 = inv[t * 2], p1 = inv[t * 2 + 1];
  union { uint4 v; unsigned short us[8]; } a, b;
  a.v = *(const uint4*)(P + (size_t)p0 * HID + c);
  float f[8];
#pragma unroll
  for (int j = 0; j < 8; ++j) f[j] = __uint_as_float((unsigned)a.us[j] << 16);
  if (p1 >= 0) {
    b.v = *(const uint4*)(P + (size_t)p1 * HID + c);
#pragma unroll
    for (int j = 0; j < 8; ++j) f[j] += __uint_as_float((unsigned)b.us[j] << 16);
  }
  float4 lo = {f[0], f[1], f[2], f[3]}, hi = {f[4], f[5], f[6], f[7]};
  *(float4*)(out + (size_t)t * HID + c) = lo;
  *(float4*)(out + (size_t)t * HID + c + 4) = hi;
}

extern "C" void kernel_launch(void* const* d_in, const int* in_sizes, int n_in,
                              void* d_out, int out_size, void* d_ws, size_t ws_size,
                              hipStream_t stream) {
  const float* hs_f  = (const float*)d_in[0];
  const float* w13_f = (const float*)d_in[1];
  const float* w2_f  = (const float*)d_in[2];
  const int*   ids   = (const int*)d_in[3];
  const float* wts   = (const float*)d_in[4];
  float* out = (float*)d_out;
  char* ws = (char*)d_ws;

  // workspace layout (bytes)
  unsigned short* hs_b  = (unsigned short*)(ws);                 // 16,777,216
  unsigned short* w13_b = (unsigned short*)(ws + 16777216);      // 92,274,688
  unsigned short* w2_b  = (unsigned short*)(ws + 109051904);     // 46,137,344
  unsigned short* act   = (unsigned short*)(ws + 155189248);     // 25,952,256
  float* R              = (float*)(ws + 181141504);              // 131,072
  int*   tl             = (int*)(ws + 181272576);                // 36,864
  int*   inv            = (int*)(ws + 181309440);                // 32,768
  int*   meta           = (int*)(ws + 181342208);                // counts[8], offs[9], cursor[8]
  // partial aliases w13_b's region (dead after gemm1; stream-ordered reuse):
  unsigned short* partial = (unsigned short*)(ws + 16777216);    // 37.7MB < 92.3MB
  int* counts = meta;
  int* offs   = meta + 8;
  int* cursor = meta + 17;

  hipMemsetAsync(meta, 0, 32 * sizeof(int), stream);

  // merged hs+w13 cvt + routing (tail 16 blocks); w2 converts inside gemm1
  cvt2route_kernel<<<dim3(NCVT + 16), dim3(256), 0, stream>>>(
      hs_f, hs_b, w13_f, w13_b, ids, wts, R, counts);

  offsets_kernel<<<dim3(1), dim3(256), 0, stream>>>(counts, offs, cursor, tl);
  scatter_kernel<<<dim3(T_TOK / 256), dim3(256), 0, stream>>>(ids, cursor, tl, inv);

  gemm1_kernel<<<dim3(11, 16, 8), dim3(512), 0, stream>>>(hs_b, w13_b, act, tl, offs, w2_f, w2_b);
  gemm2_kernel<<<dim3(8, 16, 8), dim3(512), 0, stream>>>(act, w2_b, R, tl, offs, partial);
  combine_kernel<<<dim3(T_TOK * (HID / 8) / 256), dim3(256), 0, stream>>>(partial, inv, out);
}

// Round 8
// 297.204 us; speedup vs baseline: 1.2549x; 1.2549x over previous
//
#include <hip/hip_runtime.h>
#include <hip/hip_bf16.h>

// Problem constants
#define T_TOK 4096
#define HID   2048
#define INTER 1408
#define TWO_I 2816
#define NEXP  8
#define ROWCAP 9216   // 2*T + 8*128 padding headroom

#define N8_HS  1048576   // T*HID/8
#define N8_W13 5767168   // E*TWO_I*HID/8
#define NCVT   ((N8_HS + N8_W13) / 256)   // 26624 cvt blocks

using bf16x8 = __attribute__((ext_vector_type(8))) __bf16;
using f32x4  = __attribute__((ext_vector_type(4))) float;

__device__ __forceinline__ unsigned short f2bf(float f) {
  unsigned u = __float_as_uint(f);
  u += 0x7fffu + ((u >> 16) & 1u);   // RTNE
  return (unsigned short)(u >> 16);
}

__device__ __forceinline__ void gload16(const void* g, void* l) {
  __builtin_amdgcn_global_load_lds(
      (const __attribute__((address_space(1))) void*)g,
      (__attribute__((address_space(3))) void*)l, 16, 0, 0);
}

__device__ __forceinline__ uint4 pack8(float4 a, float4 b) {
  union { unsigned short us[8]; uint4 v; } o;
  o.us[0] = f2bf(a.x); o.us[1] = f2bf(a.y); o.us[2] = f2bf(a.z); o.us[3] = f2bf(a.w);
  o.us[4] = f2bf(b.x); o.us[5] = f2bf(b.y); o.us[6] = f2bf(b.z); o.us[7] = f2bf(b.w);
  return o.v;
}

// ------- merged kernel: hs cvt + w13 cvt + routing (tail blocks) -------
__global__ void cvt2route_kernel(const float* __restrict__ hs_f, unsigned short* __restrict__ hs_b,
                                 const float* __restrict__ w13_f, unsigned short* __restrict__ w13_b,
                                 const int* __restrict__ ids, const float* __restrict__ wts,
                                 float* __restrict__ R, int* __restrict__ counts) {
  int bid = blockIdx.x;
  if (bid >= NCVT) {
    int t = (bid - NCVT) * 256 + threadIdx.x;
    if (t >= T_TOK) return;
    int e0 = ids[t * 2], e1 = ids[t * 2 + 1];
    float w0 = wts[t * 2], w1 = wts[t * 2 + 1];
#pragma unroll
    for (int ee = 0; ee < NEXP; ++ee) {
      float r = (e0 == ee ? w0 : 0.0f) + (e1 == ee ? w1 : 0.0f);
      R[t * NEXP + ee] = r;
    }
    atomicAdd(&counts[e0], 1);
    if (e1 != e0) atomicAdd(&counts[e1], 1);
    return;
  }
  int i = bid * 256 + threadIdx.x;
  const float4* p;
  uint4* o;
  int j;
  if (i < N8_HS) {
    p = reinterpret_cast<const float4*>(hs_f);
    o = reinterpret_cast<uint4*>(hs_b);
    j = i;
  } else {
    p = reinterpret_cast<const float4*>(w13_f);
    o = reinterpret_cast<uint4*>(w13_b);
    j = i - N8_HS;
  }
  o[j] = pack8(p[j * 2], p[j * 2 + 1]);
}

// ---------------- padded prefix offsets + token_list fill ----------------
__global__ void offsets_kernel(const int* __restrict__ counts,
                               int* __restrict__ offs, int* __restrict__ cursor,
                               int* __restrict__ tl) {
  if (threadIdx.x == 0) {
    int o = 0;
    for (int e = 0; e < NEXP; ++e) {
      offs[e] = o;
      cursor[e] = o;
      o += (counts[e] + 127) & ~127;
    }
    offs[NEXP] = o;
  }
  for (int i = threadIdx.x; i < ROWCAP; i += 256) tl[i] = -1;
}

// ---------------- scatter tokens into per-expert lists + inverse map ----------------
__global__ void scatter_kernel(const int* __restrict__ ids,
                               int* __restrict__ cursor, int* __restrict__ tl,
                               int* __restrict__ inv) {
  int t = blockIdx.x * 256 + threadIdx.x;
  if (t >= T_TOK) return;
  int e0 = ids[t * 2], e1 = ids[t * 2 + 1];
  int p = atomicAdd(&cursor[e0], 1);
  tl[p] = t;
  inv[t * 2] = p;
  if (e1 != e0) {
    p = atomicAdd(&cursor[e1], 1);
    tl[p] = t;
    inv[t * 2 + 1] = p;
  } else {
    inv[t * 2 + 1] = -1;   // dedup: R[t,e0] already holds w0+w1
  }
}

// ===================== 256x256 8-phase GEMM machinery =====================
// LDS map (128KB): slot S in {0, 65536}; within slot:
//   Ah0 @ +0, Ah1 @ +16384, Bh0 @ +32768, Bh1 @ +49152  (each 128 rows x 128B)
// Stage: per wave 2 chunks (1KB = 8 rows) per half-tile; XOR swizzle
// (store col ^ (srow<<4), read col ^ ((row&7)<<4)) -- proven conflict-free.
// Phase protocol per iteration (2 K-tiles t0=2i slot0, t1=2i+1 slot1):
//  P1: ld a_lo,b_lo(s0); stage s1.Ah0@t1      | P5: ld a_lo,b_lo(s1); [nl] stage s0.Ah0@t0+2
//  P2: ld b_hi(s0);      stage s1.Ah1@t1      | P6: ld b_hi(s1);      [nl] stage s0.Ah1@t0+2
//  P3: ld a_hi(s0); [nl] stage s0.Bh0@t0+2    | P7: ld a_hi(s1);      [nl] stage s1.Bh0@t1+2
//  P4: [nl] stage s0.Bh1@t0+2; vmcnt(4|0)     | P8: [nl] stage s1.Bh1@t1+2; [nl] vmcnt(4)
// Each phase: BARR; setprio(1); 16 MFMA; setprio(0); BARR.
// Hand-verified: every stage target's last ds_read is >=1 barrier earlier;
// vmcnt(4) at P4/P8 drains exactly the halves needed by following phases.
// NOTE (session ledger): 6 structural variants measured off this base --
// A-direct-global (R1), persistent queue (R3), XCD-affinity queue (R4),
// fused fp32-B staging (R5), cvt-tail queue (R6), front-loaded ds_reads (R7)
// -- ALL regressed. Distributed per-phase reads + static XCD-chunked grid +
// upfront w2-cvt smear is the measured local optimum; do not re-perturb
// these axes without new counter evidence.

#define BARR do { __asm__ __volatile__("" ::: "memory"); \
                  __builtin_amdgcn_s_barrier();           \
                  __asm__ __volatile__("" ::: "memory"); } while (0)
#define VMC(n) __asm__ __volatile__("s_waitcnt vmcnt(" #n ")" ::: "memory")

#define STG(P, h, kt, slotOff, hOff)                                        \
  do {                                                                      \
    gload16(P[h][0] + (kt) * 128, smem + (slotOff) + (hOff) + chA);         \
    gload16(P[h][1] + (kt) * 128, smem + (slotOff) + (hOff) + chA + 1024);  \
  } while (0)

#define LDA(dst, S, aq)                                                     \
  do {                                                                      \
    _Pragma("unroll") for (int mi = 0; mi < 4; ++mi) {                      \
      const char* _p = smem + (S) + wmOff + ((aq) * 64 + mi * 16 + l15) * 128; \
      dst[mi][0] = *(const bf16x8*)(_p + ko0);                              \
      dst[mi][1] = *(const bf16x8*)(_p + ko1);                              \
    }                                                                       \
  } while (0)

#define LDB(dst, S, bq)                                                     \
  do {                                                                      \
    _Pragma("unroll") for (int ni = 0; ni < 2; ++ni) {                      \
      const char* _p = smem + (S) + 32768 + wnhOff +                        \
                       (wn1 * 64 + ((bq) * 2 + ni) * 16 + l15) * 128;       \
      dst[ni][0] = *(const bf16x8*)(_p + ko0);                              \
      dst[ni][1] = *(const bf16x8*)(_p + ko1);                              \
    }                                                                       \
  } while (0)

#define MFQ(A, B, aq, bq)                                                   \
  do {                                                                      \
    __builtin_amdgcn_s_setprio(1);                                          \
    _Pragma("unroll") for (int mi = 0; mi < 4; ++mi)                        \
    _Pragma("unroll") for (int ni = 0; ni < 2; ++ni) {                      \
      acc[(aq) * 4 + mi][(bq) * 2 + ni] = __builtin_amdgcn_mfma_f32_16x16x32_bf16( \
          A[mi][0], B[ni][0], acc[(aq) * 4 + mi][(bq) * 2 + ni], 0, 0, 0);  \
      acc[(aq) * 4 + mi][(bq) * 2 + ni] = __builtin_amdgcn_mfma_f32_16x16x32_bf16( \
          A[mi][1], B[ni][1], acc[(aq) * 4 + mi][(bq) * 2 + ni], 0, 0, 0);  \
    }                                                                       \
    __builtin_amdgcn_s_setprio(0);                                          \
  } while (0)

#define EIGHT_PHASES(NIT_, NL_LIM_)                                         \
  for (int i = 0; i < (NIT_); ++i) {                                        \
    const int t0 = 2 * i, t1 = t0 + 1;                                      \
    const bool nl = (i < (NL_LIM_));                                        \
    /* P1 */                                                                \
    LDA(a_lo, 0, 0);                                                        \
    LDB(b_lo, 0, 0);                                                        \
    STG(aS, 0, t1, 65536, 0);                                               \
    BARR; MFQ(a_lo, b_lo, 0, 0); BARR;                                      \
    /* P2 */                                                                \
    LDB(b_hi, 0, 1);                                                        \
    STG(aS, 1, t1, 65536, 16384);                                           \
    BARR; MFQ(a_lo, b_hi, 0, 1); BARR;                                      \
    /* P3 */                                                                \
    LDA(a_hi, 0, 1);                                                        \
    if (nl) STG(bS, 0, t0 + 2, 0, 32768);                                   \
    BARR; MFQ(a_hi, b_hi, 1, 1); BARR;                                      \
    /* P4 */                                                                \
    if (nl) STG(bS, 1, t0 + 2, 0, 49152);                                   \
    BARR; MFQ(a_hi, b_lo, 1, 0);                                            \
    if (nl) { VMC(4); } else { VMC(0); }                                    \
    BARR;                                                                   \
    /* P5 */                                                                \
    LDA(a_lo, 65536, 0);                                                    \
    LDB(b_lo, 65536, 0);                                                    \
    if (nl) STG(aS, 0, t0 + 2, 0, 0);                                       \
    BARR; MFQ(a_lo, b_lo, 0, 0); BARR;                                      \
    /* P6 */                                                                \
    LDB(b_hi, 65536, 1);                                                    \
    if (nl) STG(aS, 1, t0 + 2, 0, 16384);                                   \
    BARR; MFQ(a_lo, b_hi, 0, 1); BARR;                                      \
    /* P7 */                                                                \
    LDA(a_hi, 65536, 1);                                                    \
    if (nl) STG(bS, 0, t1 + 2, 65536, 32768);                               \
    BARR; MFQ(a_hi, b_hi, 1, 1); BARR;                                      \
    /* P8 */                                                                \
    if (nl) STG(bS, 1, t1 + 2, 65536, 49152);                               \
    BARR; MFQ(a_hi, b_lo, 1, 0);                                            \
    if (nl) VMC(4);                                                         \
    BARR;                                                                   \
  }

#define PROLOGUE_STAGE()                                                    \
  do {                                                                      \
    STG(aS, 0, 0, 0, 0);                                                    \
    STG(aS, 1, 0, 0, 16384);                                                \
    STG(bS, 0, 0, 0, 32768);                                                \
    STG(bS, 1, 0, 0, 49152);                                                \
    STG(bS, 0, 1, 65536, 32768);                                            \
    STG(bS, 1, 1, 65536, 49152);                                            \
    VMC(4);                                                                 \
    BARR;                                                                   \
  } while (0)

// ---------------- GEMM1 (+distributed w2 cvt): act = silu(X Wg^T)*(X Wu^T) ----
// 256x256 8-phase; N-tile packs 128 gate + 128 up cols at same col range so
// silu pairing is wave-local (ni 0,1 = gate; ni 2,3 = up).
__global__ __launch_bounds__(512, 2) void gemm1_kernel(
    const unsigned short* __restrict__ hs,   // T x 2048 bf16
    const unsigned short* __restrict__ w13,  // E x 2816 x 2048 bf16
    unsigned short* __restrict__ act,        // ROWCAP x 1408 bf16
    const int* __restrict__ tl, const int* __restrict__ offs,
    const float* __restrict__ w2f, unsigned short* __restrict__ w2b) {
  const int tid = threadIdx.x;
  const int lin = blockIdx.x + 11 * (blockIdx.y + 16 * blockIdx.z);  // [0,1408)

  // ---- distributed w2 conversion (before early-exit!) ----
  {
    const float4* p = reinterpret_cast<const float4*>(w2f);
    uint4* o = reinterpret_cast<uint4*>(w2b);
    int gid = lin * 512 + tid;              // 720896 threads total
#pragma unroll
    for (int q = 0; q < 4; ++q) {
      int idx = q * 720896 + gid;           // 4*720896 = 2,883,584 uint4 = whole w2
      o[idx] = pack8(p[idx * 2], p[idx * 2 + 1]);
    }
  }

  // ---- XCD-chunked tile id: nwg = 1408, q = 176 (expert -> XCD) ----
  const int work = (lin & 7) * 176 + (lin >> 3);
  const int bz = work / 176;
  const int rem = work - bz * 176;
  const int bx = rem % 11;
  const int by = rem / 11;

  const int e = bz;
  const int rbeg = offs[e], rend = offs[e + 1];
  const int m0 = rbeg + by * 256;
  if (m0 >= rend) return;
  const int n0 = bx * 128;

  __shared__ __align__(16) char smem[131072];

  const int lane = tid & 63, wave = tid >> 6;
  const int wm = wave >> 2, wn = wave & 3;
  const int l15 = lane & 15;
  const int srow = lane >> 3;
  const int scolswz = ((lane & 7) * 16) ^ (srow << 4);
  const int chA = wave * 2048;
  const int wmOff = wm * 16384;
  const int wnhOff = (wn >> 1) * 16384;
  const int wn1 = wn & 1;
  const int rsw = (lane & 7) << 4;
  const int ko0 = ((lane >> 4) * 16) ^ rsw;
  const int ko1 = (64 + (lane >> 4) * 16) ^ rsw;

  const char* hs_b = (const char*)hs;
  const char* w13_b = (const char*)w13 + (size_t)e * (TWO_I * HID * 2);

  const char* aS[2][2];
  const char* bS[2][2];
#pragma unroll
  for (int h = 0; h < 2; ++h)
#pragma unroll
    for (int it = 0; it < 2; ++it) {
      int rl = h * 128 + (wave * 2 + it) * 8 + srow;
      int grow = m0 + rl;
      int tk = (grow < rend) ? tl[grow] : 0;
      if (tk < 0) tk = 0;
      aS[h][it] = hs_b + (size_t)tk * 4096 + scolswz;
      int wg = rl >> 6, sub = rl & 63;   // B LDS row -> w13 row (gate/up packed)
      int srcB = (sub < 32) ? (n0 + wg * 32 + sub)
                            : (INTER + n0 + wg * 32 + (sub - 32));
      bS[h][it] = w13_b + (size_t)srcB * 4096 + scolswz;
    }

  f32x4 acc[8][4] = {};
  bf16x8 a_lo[4][2], a_hi[4][2], b_lo[2][2], b_hi[2][2];

  PROLOGUE_STAGE();
  EIGHT_PHASES(16, 15);   // K = 2048 -> 32 K-tiles, 16 iterations

  // epilogue: silu(g)*u -> bf16 act.  C/D: col=lane&15, row=(lane>>4)*4+j
  const bool okst = (wm == 0) || (rend - m0 >= 256);
  if (okst) {
#pragma unroll
    for (int MI = 0; MI < 8; ++MI)
#pragma unroll
      for (int j = 0; j < 4; ++j) {
        int row = m0 + wm * 128 + MI * 16 + (lane >> 4) * 4 + j;
        size_t base = (size_t)row * INTER + n0 + wn * 32;
#pragma unroll
        for (int NI = 0; NI < 2; ++NI) {
          float g = acc[MI][NI][j], u = acc[MI][NI + 2][j];
          float s = (g / (1.0f + __expf(-g))) * u;
          act[base + NI * 16 + l15] = f2bf(s);
        }
      }
  }
}

// ---------------- GEMM2: partial[p,:] = bf16( R[tl[p],e] * (act @ w2[e]^T) ) --
__global__ __launch_bounds__(512, 2) void gemm2_kernel(
    const unsigned short* __restrict__ act,  // ROWCAP x 1408 bf16
    const unsigned short* __restrict__ w2,   // E x 2048 x 1408 bf16
    const float* __restrict__ R, const int* __restrict__ tl,
    const int* __restrict__ offs, unsigned short* __restrict__ partial) {
  const int tid = threadIdx.x;
  const int lin = blockIdx.x + 8 * (blockIdx.y + 16 * blockIdx.z);  // [0,1024)
  const int work = (lin & 7) * 128 + (lin >> 3);
  const int bz = work >> 7;
  const int rem = work & 127;
  const int bx = rem & 7;
  const int by = rem >> 3;

  const int e = bz;
  const int rbeg = offs[e], rend = offs[e + 1];
  const int m0 = rbeg + by * 256;
  if (m0 >= rend) return;
  const int n0 = bx * 256;

  __shared__ __align__(16) char smem[131072];

  const int lane = tid & 63, wave = tid >> 6;
  const int wm = wave >> 2, wn = wave & 3;
  const int l15 = lane & 15;
  const int srow = lane >> 3;
  const int scolswz = ((lane & 7) * 16) ^ (srow << 4);
  const int chA = wave * 2048;
  const int wmOff = wm * 16384;
  const int wnhOff = (wn >> 1) * 16384;
  const int wn1 = wn & 1;
  const int rsw = (lane & 7) << 4;
  const int ko0 = ((lane >> 4) * 16) ^ rsw;
  const int ko1 = (64 + (lane >> 4) * 16) ^ rsw;

  const char* act_b = (const char*)act;
  const char* w2_b = (const char*)w2 + (size_t)e * (HID * INTER * 2);

  const char* aS[2][2];
  const char* bS[2][2];
#pragma unroll
  for (int h = 0; h < 2; ++h)
#pragma unroll
    for (int it = 0; it < 2; ++it) {
      int rl = h * 128 + (wave * 2 + it) * 8 + srow;
      int grow = m0 + rl;
      if (grow >= rend) grow = rbeg;           // keep reads in-bounds
      aS[h][it] = act_b + (size_t)grow * (INTER * 2) + scolswz;
      bS[h][it] = w2_b + (size_t)(n0 + rl) * (INTER * 2) + scolswz;
    }

  f32x4 acc[8][4] = {};
  bf16x8 a_lo[4][2], a_hi[4][2], b_lo[2][2], b_hi[2][2];

  PROLOGUE_STAGE();
  EIGHT_PHASES(11, 10);   // K = 1408 -> 22 K-tiles, 11 iterations

  // epilogue: weight-scale + bf16 stores (pads get sc=0)
  const bool okst = (wm == 0) || (rend - m0 >= 256);
  if (okst) {
#pragma unroll
    for (int MI = 0; MI < 8; ++MI) {
      float sc[4];
#pragma unroll
      for (int j = 0; j < 4; ++j) {
        int row = m0 + wm * 128 + MI * 16 + (lane >> 4) * 4 + j;
        int t = tl[row];
        sc[j] = t >= 0 ? R[t * NEXP + e] : 0.0f;
      }
#pragma unroll
      for (int NI = 0; NI < 4; ++NI) {
        int col = n0 + wn * 64 + NI * 16 + l15;
#pragma unroll
        for (int j = 0; j < 4; ++j) {
          int row = m0 + wm * 128 + MI * 16 + (lane >> 4) * 4 + j;
          partial[(size_t)row * HID + col] = f2bf(acc[MI][NI][j] * sc[j]);
        }
      }
    }
  }
}

// ---------------- combine: out[t,:] = partial[inv0,:] (+ partial[inv1,:]) ----
__global__ void combine_kernel(const unsigned short* __restrict__ P,
                               const int* __restrict__ inv,
                               float* __restrict__ out) {
  int idx = blockIdx.x * 256 + threadIdx.x;   // T_TOK * HID/8 threads
  int t = idx >> 8;                            // HID/8 = 256
  int c = (idx & 255) << 3;
  int p0 = inv[t * 2], p1 = inv[t * 2 + 1];
  union { uint4 v; unsigned short us[8]; } a, b;
  a.v = *(const uint4*)(P + (size_t)p0 * HID + c);
  float f[8];
#pragma unroll
  for (int j = 0; j < 8; ++j) f[j] = __uint_as_float((unsigned)a.us[j] << 16);
  if (p1 >= 0) {
    b.v = *(const uint4*)(P + (size_t)p1 * HID + c);
#pragma unroll
    for (int j = 0; j < 8; ++j) f[j] += __uint_as_float((unsigned)b.us[j] << 16);
  }
  float4 lo = {f[0], f[1], f[2], f[3]}, hi = {f[4], f[5], f[6], f[7]};
  *(float4*)(out + (size_t)t * HID + c) = lo;
  *(float4*)(out + (size_t)t * HID + c + 4) = hi;
}

extern "C" void kernel_launch(void* const* d_in, const int* in_sizes, int n_in,
                              void* d_out, int out_size, void* d_ws, size_t ws_size,
                              hipStream_t stream) {
  const float* hs_f  = (const float*)d_in[0];
  const float* w13_f = (const float*)d_in[1];
  const float* w2_f  = (const float*)d_in[2];
  const int*   ids   = (const int*)d_in[3];
  const float* wts   = (const float*)d_in[4];
  float* out = (float*)d_out;
  char* ws = (char*)d_ws;

  // workspace layout (bytes)
  unsigned short* hs_b  = (unsigned short*)(ws);                 // 16,777,216
  unsigned short* w13_b = (unsigned short*)(ws + 16777216);      // 92,274,688
  unsigned short* w2_b  = (unsigned short*)(ws + 109051904);     // 46,137,344
  unsigned short* act   = (unsigned short*)(ws + 155189248);     // 25,952,256
  float* R              = (float*)(ws + 181141504);              // 131,072
  int*   tl             = (int*)(ws + 181272576);                // 36,864
  int*   inv            = (int*)(ws + 181309440);                // 32,768
  int*   meta           = (int*)(ws + 181342208);                // counts[8], offs[9], cursor[8]
  // partial aliases w13_b's region (dead after gemm1; stream-ordered reuse):
  unsigned short* partial = (unsigned short*)(ws + 16777216);    // 37.7MB < 92.3MB
  int* counts = meta;
  int* offs   = meta + 8;
  int* cursor = meta + 17;

  hipMemsetAsync(meta, 0, 32 * sizeof(int), stream);

  // merged hs+w13 cvt + routing (tail 16 blocks); w2 converts inside gemm1
  cvt2route_kernel<<<dim3(NCVT + 16), dim3(256), 0, stream>>>(
      hs_f, hs_b, w13_f, w13_b, ids, wts, R, counts);

  offsets_kernel<<<dim3(1), dim3(256), 0, stream>>>(counts, offs, cursor, tl);
  scatter_kernel<<<dim3(T_TOK / 256), dim3(256), 0, stream>>>(ids, cursor, tl, inv);

  gemm1_kernel<<<dim3(11, 16, 8), dim3(512), 0, stream>>>(hs_b, w13_b, act, tl, offs, w2_f, w2_b);
  gemm2_kernel<<<dim3(8, 16, 8), dim3(512), 0, stream>>>(act, w2_b, R, tl, offs, partial);
  combine_kernel<<<dim3(T_TOK * (HID / 8) / 256), dim3(256), 0, stream>>>(partial, inv, out);
}